// Round 5
// baseline (324.460 us; speedup 1.0000x reference)
//
#include <hip/hip_runtime.h>

// YOLO detection head post-process.
// Input : x (B=64, C=255, 52, 52) f32   [C = 3 anchors * 85]
// Output: (B, 3*52*52, 85) f32
// out[((b*3+a)*2704 + y*52 + x)*85 + e]:
//   e==0: (sigmoid(v) + x) * 8
//   e==1: (sigmoid(v) + y) * 8
//   e==2: exp(v) * AW[a]        (anchor/stride * stride cancels)
//   e==3: exp(v) * AH[a]
//   e>=4: sigmoid(v)
//
// R4 tiling (unchanged from last round): 4 grid rows per block, 832 B
// contiguous reads per channel; LDS 71 KB -> 2 blocks/CU, 512 threads.
// NEW this round: non-temporal output stores. Output (176.5 MB) is never
// re-read by the kernel; NT stores keep it from allocating in L2/L3, so
// the 176 MB input stays L3-resident (absorbing line over-fetch) and the
// write stream behaves like the pure-write fill (6.5 TB/s) instead of
// thrashing the cache hierarchy.

#define GG   2704      // 52*52
#define CH   85
#define R    4         // grid rows per block
#define SP   (R * 52)  // 208 spatial positions per tile
#define LSTR 209       // odd -> conflict-free transposed LDS reads (2-way max)
#define NT   512

__global__ __launch_bounds__(NT) void det_kernel(const float* __restrict__ in,
                                                 float* __restrict__ out) {
    __shared__ float lds[CH * LSTR];   // 71,060 B

    const int tile = blockIdx.x;   // 0..12: rows [tile*4, tile*4+4)
    const int a    = blockIdx.y;   // anchor 0..2
    const int b    = blockIdx.z;   // batch 0..63
    const int tid  = threadIdx.x;

    // ---- Stage: 85 channels x 832 B contiguous chunks (float4) -> LDS ----
    // chunk of channel c starts at float4 offset c*676 within the tile view
    const float4* in4 = (const float4*)(in + ((size_t)b * 255 + (size_t)a * 85) * GG
                                           + (size_t)tile * SP);
    {
        // 85 * 52 = 4420 float4s; 8 full passes of 512 + tail of 324
        int l = tid;
        #pragma unroll
        for (int k = 0; k < 8; ++k) {
            const int c  = l / 52;
            const int s4 = l - c * 52;
            const float4 v = in4[c * 676 + s4];
            float* dst = &lds[c * LSTR + (s4 << 2)];
            dst[0] = v.x; dst[1] = v.y; dst[2] = v.z; dst[3] = v.w;
            l += NT;
        }
        if (l < CH * (SP / 4)) {
            const int c  = l / 52;
            const int s4 = l - c * 52;
            const float4 v = in4[c * 676 + s4];
            float* dst = &lds[c * LSTR + (s4 << 2)];
            dst[0] = v.x; dst[1] = v.y; dst[2] = v.z; dst[3] = v.w;
        }
    }
    __syncthreads();

    // ---- Transform + store: e fixed per thread, all selection hoisted ----
    // Thread tid (<510) owns channel e = tid%85, local spatial s = tid/85,
    // s advances by 6 per pass. Output offset o = s*85 + e = tid + 510*k:
    // consecutive lanes -> coalesced contiguous NT stores.
    if (tid < 510) {
        const int e = tid % 85;
        int s       = tid / 85;            // 0..5

        const float AW[3] = {10.f, 16.f, 33.f};
        const float AH[3] = {13.f, 30.f, 23.f};

        const bool  isexp = (e == 2) | (e == 3);
        const float sgn   = isexp ? 1.f : -1.f;
        float scale;
        if (e < 2)       scale = 8.f;
        else if (e == 2) scale = AW[a];
        else if (e == 3) scale = AH[a];
        else             scale = 1.f;
        const float cx8   = (e == 0) ? 8.f : 0.f;   // coeff on grid x
        const float cy8   = (e == 1) ? 8.f : 0.f;   // coeff on grid y
        const float ybase = (float)(tile * R);

        float* op = out + ((size_t)((b * 3 + a) * GG) + (size_t)tile * SP) * CH;

        int x  = s;      // s < 52 initially -> x = s, yl = 0
        int yl = 0;
        #pragma unroll 2
        for (int o = tid; o < SP * CH; o += 510) {   // 17,680 outputs
            float v = lds[e * LSTR + s];
            float t = __expf(sgn * v);                         // v_mul + v_exp
            float w = isexp ? t : __builtin_amdgcn_rcpf(1.f + t);
            float addend = fmaf(cx8, (float)x, cy8 * (ybase + (float)yl));
            __builtin_nontemporal_store(fmaf(scale, w, addend), op + o);
            s += 6;
            x += 6;
            if (x >= 52) { x -= 52; yl += 1; }   // step 6 < 52: one wrap max
        }
    }
}

extern "C" void kernel_launch(void* const* d_in, const int* in_sizes, int n_in,
                              void* d_out, int out_size, void* d_ws, size_t ws_size,
                              hipStream_t stream) {
    const float* x = (const float*)d_in[0];
    float* out = (float*)d_out;
    dim3 grid(13, 3, 64);   // 13 row-tiles x 3 anchors x 64 batch = 2496 blocks
    det_kernel<<<grid, NT, 0, stream>>>(x, out);
}

// Round 6
// 300.705 us; speedup vs baseline: 1.0790x; 1.0790x over previous
//
#include <hip/hip_runtime.h>

// YOLO detection head post-process.
// Input : x (B=64, C=255, 52, 52) f32   [C = 3 anchors * 85]
// Output: (B, 3*52*52, 85) f32
// out[((b*3+a)*2704 + y*52 + x)*85 + e]:
//   e==0: (sigmoid(v) + x) * 8
//   e==1: (sigmoid(v) + y) * 8
//   e==2: exp(v) * AW[a]        (anchor/stride * stride cancels)
//   e==3: exp(v) * AH[a]
//   e>=4: sigmoid(v)
//
// R2 tiling: 2 grid rows per block -> 416 B contiguous reads per channel
// (~1.15x line over-fetch, largely L3-absorbed) AND 35.7 KB LDS ->
// 4 blocks/CU x 8 waves = 32 waves/CU (100% occupancy) for stage/transform
// overlap across blocks. NT stores reverted (R5: 83 -> 130 us regression).

#define GG   2704      // 52*52
#define CH   85
#define R    2         // grid rows per block
#define SP   (R * 52)  // 104 spatial positions per tile
#define LSTR 105       // odd -> conflict-free transposed LDS reads (~2-way, free)
#define NT   512

__global__ __launch_bounds__(NT) void det_kernel(const float* __restrict__ in,
                                                 float* __restrict__ out) {
    __shared__ float lds[CH * LSTR];   // 35,700 B -> 4 blocks/CU

    const int tile = blockIdx.x;   // 0..25: rows [tile*2, tile*2+2)
    const int a    = blockIdx.y;   // anchor 0..2
    const int b    = blockIdx.z;   // batch 0..63
    const int tid  = threadIdx.x;

    // ---- Stage: 85 channels x 416 B contiguous chunks (float4) -> LDS ----
    // chunk of channel c starts at float4 offset c*676 within the tile view
    const float4* in4 = (const float4*)(in + ((size_t)b * 255 + (size_t)a * 85) * GG
                                           + (size_t)tile * SP);
    {
        // 85 * 26 = 2210 float4s; 4 full passes of 512 + tail of 162
        int l = tid;
        #pragma unroll
        for (int k = 0; k < 4; ++k) {
            const int c  = l / 26;
            const int s4 = l - c * 26;
            const float4 v = in4[c * 676 + s4];
            float* dst = &lds[c * LSTR + (s4 << 2)];
            dst[0] = v.x; dst[1] = v.y; dst[2] = v.z; dst[3] = v.w;
            l += NT;
        }
        if (l < CH * (SP / 4)) {
            const int c  = l / 26;
            const int s4 = l - c * 26;
            const float4 v = in4[c * 676 + s4];
            float* dst = &lds[c * LSTR + (s4 << 2)];
            dst[0] = v.x; dst[1] = v.y; dst[2] = v.z; dst[3] = v.w;
        }
    }
    __syncthreads();

    // ---- Transform + store: e fixed per thread, all selection hoisted ----
    // Thread tid (<510) owns channel e = tid%85, local spatial s = tid/85,
    // s advances by 6 per pass. Output offset o = s*85 + e = tid + 510*k:
    // consecutive lanes -> coalesced contiguous stores.
    if (tid < 510) {
        const int e = tid % 85;
        int s       = tid / 85;            // 0..5

        const float AW[3] = {10.f, 16.f, 33.f};
        const float AH[3] = {13.f, 30.f, 23.f};

        const bool  isexp = (e == 2) | (e == 3);
        const float sgn   = isexp ? 1.f : -1.f;
        float scale;
        if (e < 2)       scale = 8.f;
        else if (e == 2) scale = AW[a];
        else if (e == 3) scale = AH[a];
        else             scale = 1.f;
        const float cx8   = (e == 0) ? 8.f : 0.f;   // coeff on grid x
        const float cy8   = (e == 1) ? 8.f : 0.f;   // coeff on grid y
        const float ybase = (float)(tile * R);

        float* op = out + ((size_t)((b * 3 + a) * GG) + (size_t)tile * SP) * CH;

        int x  = s;      // s < 52 initially -> x = s, yl = 0
        int yl = 0;
        #pragma unroll 2
        for (int o = tid; o < SP * CH; o += 510) {   // 8,840 outputs
            float v = lds[e * LSTR + s];
            float t = __expf(sgn * v);                         // v_mul + v_exp
            float w = isexp ? t : __builtin_amdgcn_rcpf(1.f + t);
            float addend = fmaf(cx8, (float)x, cy8 * (ybase + (float)yl));
            op[o] = fmaf(scale, w, addend);
            s += 6;
            x += 6;
            if (x >= 52) { x -= 52; yl += 1; }   // step 6 < 52: one wrap max
        }
    }
}

extern "C" void kernel_launch(void* const* d_in, const int* in_sizes, int n_in,
                              void* d_out, int out_size, void* d_ws, size_t ws_size,
                              hipStream_t stream) {
    const float* x = (const float*)d_in[0];
    float* out = (float*)d_out;
    dim3 grid(26, 3, 64);   // 26 row-tiles x 3 anchors x 64 batch = 4992 blocks
    det_kernel<<<grid, NT, 0, stream>>>(x, out);
}